// Round 2
// baseline (1406.194 us; speedup 1.0000x reference)
//
#include <hip/hip_runtime.h>
#include <cmath>

// SparseCausalAttentionBlock on MI355X (gfx950).
// Chunked-by-batch pipeline (chunk count chosen at runtime from ws_size):
//   conv(x->bf16) -> GEMM(qkv) -> local windowed attn -> GEMM(out+res_x -> x1b)
//   -> GEMM(qg) -> global attn(kvg precomputed) -> GEMM(gout+res_x1 -> x2b)
//   -> LN1 -> GEMM(ffn1,gelu) -> GEMM(ffn2+res_xn -> d_out fp32) -> LN2 in place.
// GEMMs: m97-style bf16 MFMA 128x128x32 tile, global_load_lds width=16.

typedef unsigned short u16;
typedef unsigned int u32;
typedef __bf16 bf16_t;
typedef bf16_t bf16x8 __attribute__((ext_vector_type(8)));
typedef float f32x4 __attribute__((ext_vector_type(4)));

#define DEV __device__ __forceinline__

DEV u16 f2b(float f) {  // fp32 -> bf16 RNE
  u32 u = __float_as_uint(f);
  u32 r = u + 0x7fffu + ((u >> 16) & 1u);
  return (u16)(r >> 16);
}
DEV float b2f(u16 b) { return __uint_as_float(((u32)b) << 16); }

DEV void g2l16(const void* g, void* l) {
  // async global->LDS, 16B/lane; LDS dest = wave-uniform base + lane*16
  __builtin_amdgcn_global_load_lds((const __attribute__((address_space(1))) void*)g,
                                   (__attribute__((address_space(3))) void*)l,
                                   16, 0, 0);
}

// ---------------- fp32 -> bf16 converter (2048 elems / block) ---------------
__global__ __launch_bounds__(256) void conv1(const float* __restrict__ s,
                                             u16* __restrict__ d) {
  size_t idx = ((size_t)blockIdx.x * 256 + threadIdx.x) * 8;
  float4 a = *(const float4*)(s + idx);
  float4 b = *(const float4*)(s + idx + 4);
  float v[8] = {a.x, a.y, a.z, a.w, b.x, b.y, b.z, b.w};
  union { u16 q[8]; uint4 u; } pk;
#pragma unroll
  for (int i = 0; i < 8; ++i) pk.q[i] = f2b(v[i]);
  *(uint4*)(d + idx) = pk.u;
}

// ---------------- bf16 MFMA GEMM: C = A @ B^T (+bias)(+res)(gelu) ----------
// A:[M][K] bf16, B:[N][K] bf16. Tile 128x128x32, 256 thr = 4 waves (2x2).
template <bool GELU, bool RES32, bool RESB, bool OUT32, bool OUTB>
__global__ __launch_bounds__(256) void gemm_bt(
    const u16* __restrict__ A, const u16* __restrict__ B,
    const float* __restrict__ bias, const float* __restrict__ res32,
    const u16* __restrict__ resb, float* __restrict__ out32,
    u16* __restrict__ outb, int M, int N, int K) {
  __shared__ u16 lA[128 * 32];
  __shared__ u16 lB[128 * 32];
  const int tid = threadIdx.x;
  const int lane = tid & 63, wv = tid >> 6;
  const int m0 = blockIdx.y * 128, n0 = blockIdx.x * 128;
  const int wm = (wv >> 1) * 64, wn = (wv & 1) * 64;
  const int lrow = lane & 15;
  const int koff = (lane >> 4) * 8;
  const int rA = tid >> 2;       // staging row (per it: +64)
  const int cA = (tid & 3) * 8;  // staging col (elements)

  f32x4 zero4 = {0.f, 0.f, 0.f, 0.f};
  f32x4 acc[4][4];
#pragma unroll
  for (int a = 0; a < 4; ++a)
#pragma unroll
    for (int b = 0; b < 4; ++b) acc[a][b] = zero4;

  for (int kt = 0; kt < K; kt += 32) {
    const u16* gA = A + (size_t)m0 * K + kt;
    const u16* gB = B + (size_t)n0 * K + kt;
#pragma unroll
    for (int it = 0; it < 2; ++it) {
      int row = it * 64 + rA;
      int c = it * 256 + tid;
      g2l16(gA + (size_t)row * K + cA, (char*)lA + (size_t)c * 16);
      g2l16(gB + (size_t)row * K + cA, (char*)lB + (size_t)c * 16);
    }
    __syncthreads();  // drains vmcnt (global_load_lds) per m97 structure
    bf16x8 af[4], bfr[4];
#pragma unroll
    for (int f = 0; f < 4; ++f)
      af[f] = *(const bf16x8*)&lA[(wm + f * 16 + lrow) * 32 + koff];
#pragma unroll
    for (int f = 0; f < 4; ++f)
      bfr[f] = *(const bf16x8*)&lB[(wn + f * 16 + lrow) * 32 + koff];
#pragma unroll
    for (int fm = 0; fm < 4; ++fm)
#pragma unroll
      for (int fn = 0; fn < 4; ++fn)
        acc[fm][fn] = __builtin_amdgcn_mfma_f32_16x16x32_bf16(af[fm], bfr[fn], acc[fm][fn], 0, 0, 0);
    __syncthreads();
  }

#pragma unroll
  for (int fn = 0; fn < 4; ++fn) {
    int gcol = n0 + wn + fn * 16 + lrow;  // C/D: col = lane&15 (m89 layout)
    float bia = bias[gcol];
#pragma unroll
    for (int fm = 0; fm < 4; ++fm) {
#pragma unroll
      for (int r = 0; r < 4; ++r) {
        int grow = m0 + wm + fm * 16 + (lane >> 4) * 4 + r;  // row = quad*4+reg
        size_t gi = (size_t)grow * N + gcol;
        float c = acc[fm][fn][r] + bia;
        if (RES32) c += res32[gi];
        if (RESB) c += b2f(resb[gi]);
        if (GELU) c = 0.5f * c * (1.0f + erff(c * 0.70710678118654752f));
        if (OUT32) out32[gi] = c;
        if (OUTB) outb[gi] = f2b(c);
      }
    }
  }
}

// ---------------- local windowed causal attention (window=64) ---------------
// qkv: [rows][1536] bf16 (q|k|v). One wave per (b,h,i). Keys j=i-64..i.
__global__ __launch_bounds__(256) void local_attn(const u16* __restrict__ qkv,
                                                  u16* __restrict__ outb) {
  const int lane = threadIdx.x & 63;
  const int gid = blockIdx.x * 4 + (threadIdx.x >> 6);
  const int i = gid & 511, bh = gid >> 9, h = bh & 7, b = bh >> 3;
  const size_t base = (size_t)b * 512 * 1536;
  const int hc = h * 64;

  float qv = b2f(qkv[base + (size_t)i * 1536 + hc + lane]) * 0.125f;

  // diagonal key j=i: full-wave dot reduce
  float sd = qv * b2f(qkv[base + (size_t)i * 1536 + 512 + hc + lane]);
#pragma unroll
  for (int o = 32; o; o >>= 1) sd += __shfl_xor(sd, o);

  // lane l -> key j = i-64+l
  const int j = i - 64 + lane;
  const int jc = j < 0 ? 0 : j;
  const u16* Kr = qkv + base + (size_t)jc * 1536 + 512 + hc;
  float s0 = 0.f, s1 = 0.f;
#pragma unroll
  for (int c = 0; c < 8; ++c) {
    union { u16 q[8]; uint4 u; } kk;
    kk.u = *(const uint4*)(Kr + c * 8);
#pragma unroll
    for (int t = 0; t < 8; ++t) {
      float qd = __shfl(qv, c * 8 + t);
      if (t & 1) s1 += qd * b2f(kk.q[t]); else s0 += qd * b2f(kk.q[t]);
    }
  }
  const bool valid = (j >= 0);
  float sv = valid ? (s0 + s1) : -1e30f;
  float mx = sv;
#pragma unroll
  for (int o = 32; o; o >>= 1) mx = fmaxf(mx, __shfl_xor(mx, o));
  mx = fmaxf(mx, sd);
  float p = valid ? __expf(sv - mx) : 0.f;
  float pd = __expf(sd - mx);
  float sum = p;
#pragma unroll
  for (int o = 32; o; o >>= 1) sum += __shfl_xor(sum, o);
  const float inv = 1.f / (sum + pd);

  // PV: lane = d. Coalesced V rows.
  float o0 = pd * b2f(qkv[base + (size_t)i * 1536 + 1024 + hc + lane]);
  float o1 = 0.f;
#pragma unroll
  for (int l = 0; l < 64; ++l) {
    float pl = __shfl(p, l);
    int jl = i - 64 + l; int jlc = jl < 0 ? 0 : jl;
    float vv = b2f(qkv[base + (size_t)jlc * 1536 + 1024 + hc + lane]);
    if (l & 1) o1 += pl * vv; else o0 += pl * vv;
  }
  outb[((size_t)(b * 512 + i)) * 512 + hc + lane] = f2b((o0 + o1) * inv);
}

// ---------------- global attention over 32 anchors --------------------------
// qg: [rows][512] bf16; kvg: [nb*32][1024] bf16 (k|v). One wave per query.
__global__ __launch_bounds__(256) void global_attn(const u16* __restrict__ qg,
                                                   const u16* __restrict__ kvg,
                                                   u16* __restrict__ outb) {
  const int lane = threadIdx.x & 63;
  const int gid = blockIdx.x * 4 + (threadIdx.x >> 6);
  const int i = gid & 511, bh = gid >> 9, h = bh & 7, b = bh >> 3;
  const int hc = h * 64;

  float qv = b2f(qg[((size_t)(b * 512 + i)) * 512 + hc + lane]) * 0.125f;
  const int l = lane & 31;  // lanes 32-63 duplicate keys 0-31
  const u16* Kr = kvg + ((size_t)(b * 32 + l)) * 1024 + hc;
  float s0 = 0.f, s1 = 0.f;
#pragma unroll
  for (int c = 0; c < 8; ++c) {
    union { u16 q[8]; uint4 u; } kk;
    kk.u = *(const uint4*)(Kr + c * 8);
#pragma unroll
    for (int t = 0; t < 8; ++t) {
      float qd = __shfl(qv, c * 8 + t);
      if (t & 1) s1 += qd * b2f(kk.q[t]); else s0 += qd * b2f(kk.q[t]);
    }
  }
  float s = s0 + s1;
  float mx = s;
#pragma unroll
  for (int o = 16; o; o >>= 1) mx = fmaxf(mx, __shfl_xor(mx, o));
  float p = __expf(s - mx);
  float sum = p;
#pragma unroll
  for (int o = 16; o; o >>= 1) sum += __shfl_xor(sum, o);
  const float inv = 1.f / sum;

  float o0 = 0.f, o1 = 0.f;
#pragma unroll
  for (int l2 = 0; l2 < 32; ++l2) {
    float pl = __shfl(p, l2);
    float vv = b2f(kvg[((size_t)(b * 32 + l2)) * 1024 + 512 + hc + lane]);
    if (l2 & 1) o1 += pl * vv; else o0 += pl * vv;
  }
  outb[((size_t)(b * 512 + i)) * 512 + hc + lane] = f2b((o0 + o1) * inv);
}

// ---------------- LayerNorm over 512 cols, one wave per row -----------------
__global__ __launch_bounds__(256) void ln_b2b(const u16* __restrict__ in,
                                              const float* __restrict__ gg,
                                              const float* __restrict__ bb,
                                              u16* __restrict__ outb) {
  const int lane = threadIdx.x & 63;
  const size_t row = (size_t)blockIdx.x * 4 + (threadIdx.x >> 6);
  union { u16 q[8]; uint4 u; } pk;
  pk.u = *(const uint4*)(in + row * 512 + lane * 8);
  float v[8];
#pragma unroll
  for (int e = 0; e < 8; ++e) v[e] = b2f(pk.q[e]);
  float sm = 0.f, sq = 0.f;
#pragma unroll
  for (int e = 0; e < 8; ++e) { sm += v[e]; sq += v[e] * v[e]; }
#pragma unroll
  for (int o = 32; o; o >>= 1) { sm += __shfl_xor(sm, o); sq += __shfl_xor(sq, o); }
  float mean = sm * (1.0f / 512.0f);
  float var = sq * (1.0f / 512.0f) - mean * mean;
  float rs = rsqrtf(var + 1e-5f);
  float4 ga = *(const float4*)(gg + lane * 8);
  float4 gb = *(const float4*)(gg + lane * 8 + 4);
  float4 ba = *(const float4*)(bb + lane * 8);
  float4 bbv = *(const float4*)(bb + lane * 8 + 4);
  float gv[8] = {ga.x, ga.y, ga.z, ga.w, gb.x, gb.y, gb.z, gb.w};
  float bv[8] = {ba.x, ba.y, ba.z, ba.w, bbv.x, bbv.y, bbv.z, bbv.w};
  union { u16 q[8]; uint4 u; } po;
#pragma unroll
  for (int e = 0; e < 8; ++e) po.q[e] = f2b((v[e] - mean) * rs * gv[e] + bv[e]);
  *(uint4*)(outb + row * 512 + lane * 8) = po.u;
}

__global__ __launch_bounds__(256) void ln_f2f(const float* __restrict__ in,
                                              const float* __restrict__ gg,
                                              const float* __restrict__ bb,
                                              float* __restrict__ out) {
  const int lane = threadIdx.x & 63;
  const size_t row = (size_t)blockIdx.x * 4 + (threadIdx.x >> 6);
  const float* p = in + row * 512 + lane * 8;
  float4 a = *(const float4*)p;
  float4 b = *(const float4*)(p + 4);
  float v[8] = {a.x, a.y, a.z, a.w, b.x, b.y, b.z, b.w};
  float sm = 0.f, sq = 0.f;
#pragma unroll
  for (int e = 0; e < 8; ++e) { sm += v[e]; sq += v[e] * v[e]; }
#pragma unroll
  for (int o = 32; o; o >>= 1) { sm += __shfl_xor(sm, o); sq += __shfl_xor(sq, o); }
  float mean = sm * (1.0f / 512.0f);
  float var = sq * (1.0f / 512.0f) - mean * mean;
  float rs = rsqrtf(var + 1e-5f);
  float4 ga = *(const float4*)(gg + lane * 8);
  float4 gb = *(const float4*)(gg + lane * 8 + 4);
  float4 ba = *(const float4*)(bb + lane * 8);
  float4 bbv = *(const float4*)(bb + lane * 8 + 4);
  float gv[8] = {ga.x, ga.y, ga.z, ga.w, gb.x, gb.y, gb.z, gb.w};
  float bv[8] = {ba.x, ba.y, ba.z, ba.w, bbv.x, bbv.y, bbv.z, bbv.w};
  float r[8];
#pragma unroll
  for (int e = 0; e < 8; ++e) r[e] = (v[e] - mean) * rs * gv[e] + bv[e];
  float4 r1 = {r[0], r[1], r[2], r[3]};
  float4 r2 = {r[4], r[5], r[6], r[7]};
  *(float4*)(out + row * 512 + lane * 8) = r1;
  *(float4*)(out + row * 512 + lane * 8 + 4) = r2;
}

// ---------------- driver -----------------------------------------------------
extern "C" void kernel_launch(void* const* d_in, const int* in_sizes, int n_in,
                              void* d_out, int out_size, void* d_ws, size_t ws_size,
                              hipStream_t stream) {
  const float* x      = (const float*)d_in[0];
  const float* anchors= (const float*)d_in[1];
  const float* lw_in  = (const float*)d_in[2];
  const float* lb_in  = (const float*)d_in[3];
  const float* lw_out = (const float*)d_in[4];
  const float* lb_out = (const float*)d_in[5];
  const float* gw_in  = (const float*)d_in[6];
  const float* gb_in  = (const float*)d_in[7];
  const float* gw_out = (const float*)d_in[8];
  const float* gb_out = (const float*)d_in[9];
  const float* w1     = (const float*)d_in[10];
  const float* b1     = (const float*)d_in[11];
  const float* w2     = (const float*)d_in[12];
  const float* b2     = (const float*)d_in[13];
  const float* g1     = (const float*)d_in[14];
  const float* be1    = (const float*)d_in[15];
  const float* g2     = (const float*)d_in[16];
  const float* be2    = (const float*)d_in[17];
  (void)in_sizes; (void)n_in; (void)out_size;
  float* out = (float*)d_out;

  // ---- fixed weight region (14.68 MB) ----
  char* ws = (char*)d_ws;
  size_t o = 0;
  auto nxt = [&](size_t bytes) { char* p = ws + o; o += bytes; return p; };
  u16* lwib = (u16*)nxt((size_t)1536 * 512 * 2);
  u16* lwob = (u16*)nxt((size_t)512 * 512 * 2);
  u16* gwib = (u16*)nxt((size_t)1536 * 512 * 2);
  u16* gwob = (u16*)nxt((size_t)512 * 512 * 2);
  u16* w1b  = (u16*)nxt((size_t)2048 * 512 * 2);
  u16* w2b  = (u16*)nxt((size_t)512 * 2048 * 2);
  u16* ab   = (u16*)nxt((size_t)2048 * 512 * 2);
  u16* kvgb = (u16*)nxt((size_t)2048 * 1024 * 2);
  const size_t wbytes = o;  // 14,680,064

  // ---- choose chunk count so workspace fits ws_size ----
  // per-chunk: BIG = Mc*4096 B (qkv Mc*3072 | scratch S Mc*1024; later h Mc*4096),
  //            P = Mc*1024, Q = Mc*1024.
  int nc = 1;
  while (wbytes + (size_t)(32768 / nc) * 6144 > ws_size && nc < 32) nc <<= 1;
  const int Mc = 32768 / nc;
  u16* BIGb = (u16*)nxt((size_t)Mc * 4096);
  u16* Pb   = (u16*)nxt((size_t)Mc * 1024);
  u16* Qb   = (u16*)nxt((size_t)Mc * 1024);
  u16* Sb   = BIGb + (size_t)Mc * 1536;  // scratch region inside BIG (after qkv)

  // ---- weights + anchors to bf16 (once) ----
  conv1<<<384, 256, 0, stream>>>(lw_in, lwib);
  conv1<<<128, 256, 0, stream>>>(lw_out, lwob);
  conv1<<<384, 256, 0, stream>>>(gw_in, gwib);
  conv1<<<128, 256, 0, stream>>>(gw_out, gwob);
  conv1<<<512, 256, 0, stream>>>(w1, w1b);
  conv1<<<512, 256, 0, stream>>>(w2, w2b);
  conv1<<<512, 256, 0, stream>>>(anchors, ab);
  // kvg = anchors @ [wk;wv]^T + [bk;bv]   [2048 x 1024]
  gemm_bt<false, false, false, false, true><<<dim3(8, 16), 256, 0, stream>>>(
      ab, gwib + 512 * 512, gb_in + 512, nullptr, nullptr, nullptr, kvgb, 2048, 1024, 512);

  for (int ck = 0; ck < nc; ++ck) {
    const size_t r0 = (size_t)ck * Mc;  // row offset (rows = b*512+s)
    const float* xck = x + r0 * 512;
    // 1. x chunk -> bf16 (P)
    conv1<<<Mc / 4, 256, 0, stream>>>(xck, Pb);
    // 2. qkv = xb @ lw_in^T + lb_in   [Mc x 1536] -> BIG
    gemm_bt<false, false, false, false, true><<<dim3(12, Mc / 128), 256, 0, stream>>>(
        Pb, lwib, lb_in, nullptr, nullptr, nullptr, BIGb, Mc, 1536, 512);
    // 3. local windowed attention -> S
    local_attn<<<Mc * 2, 256, 0, stream>>>(BIGb, Sb);
    // 4. x1b = x + attn @ lw_out^T + lb_out  (bf16 -> Q)
    gemm_bt<false, true, false, false, true><<<dim3(4, Mc / 128), 256, 0, stream>>>(
        Sb, lwob, lb_out, xck, nullptr, nullptr, Qb, Mc, 512, 512);
    // 5. qg = x1b @ wq^T + bq  -> P (xb dead)
    gemm_bt<false, false, false, false, true><<<dim3(4, Mc / 128), 256, 0, stream>>>(
        Qb, gwib, gb_in, nullptr, nullptr, nullptr, Pb, Mc, 512, 512);
    // 6. global attention -> S (qkv dead)
    global_attn<<<Mc * 2, 256, 0, stream>>>(Pb, kvgb + (r0 / 512) * 32 * 1024, Sb);
    // 7. x2b = x1b + gattn @ gw_out^T + gb_out  -> P (qg dead)
    gemm_bt<false, false, true, false, true><<<dim3(4, Mc / 128), 256, 0, stream>>>(
        Sb, gwob, gb_out, nullptr, Qb, nullptr, Pb, Mc, 512, 512);
    // 8. LN1: xnb = LN(x2b) -> Q (x1b dead)
    ln_b2b<<<Mc / 4, 256, 0, stream>>>(Pb, g1, be1, Qb);
    // 9. h = gelu(xnb @ w1^T + b1)  [Mc x 2048] -> BIG (qkv+S dead)
    gemm_bt<true, false, false, false, true><<<dim3(16, Mc / 128), 256, 0, stream>>>(
        Qb, w1b, b1, nullptr, nullptr, nullptr, BIGb, Mc, 2048, 512);
    // 10. t = xnb + h @ w2^T + b2 -> d_out chunk (fp32)
    gemm_bt<false, false, true, true, false><<<dim3(4, Mc / 128), 256, 0, stream>>>(
        BIGb, w2b, b2, nullptr, Qb, out + r0 * 512, nullptr, Mc, 512, 2048);
    // 11. LN2 in place on d_out chunk
    ln_f2f<<<Mc / 4, 256, 0, stream>>>(out + r0 * 512, g2, be2, out + r0 * 512);
  }
}

// Round 4
// 750.059 us; speedup vs baseline: 1.8748x; 1.8748x over previous
//
#include <hip/hip_runtime.h>
#include <cmath>

// SparseCausalAttentionBlock on MI355X (gfx950).
// Round 4: fix local_attn_mfma PV key-offset bug (wave w must read V keys at
// +16*w in the shared tile; R3 read from offset 0 for all waves -> 3/4 of
// rows used shifted V, absmax 0.94). V tile widened to 144 keys so wave 3's
// zero-padded P columns still hit initialized LDS. Rest unchanged from R2/R3.

typedef unsigned short u16;
typedef unsigned int u32;
typedef __bf16 bf16_t;
typedef bf16_t bf16x8 __attribute__((ext_vector_type(8)));
typedef float f32x4 __attribute__((ext_vector_type(4)));

#define DEV __device__ __forceinline__

DEV u16 f2b(float f) {  // fp32 -> bf16 RNE
  u32 u = __float_as_uint(f);
  u32 r = u + 0x7fffu + ((u >> 16) & 1u);
  return (u16)(r >> 16);
}
DEV float b2f(u16 b) { return __uint_as_float(((u32)b) << 16); }

DEV void g2l16(const void* g, void* l) {
  // async global->LDS, 16B/lane; LDS dest = wave-uniform base + lane*16
  __builtin_amdgcn_global_load_lds((const __attribute__((address_space(1))) void*)g,
                                   (__attribute__((address_space(3))) void*)l,
                                   16, 0, 0);
}

// ---------------- fp32 -> bf16 converter (2048 elems / block) ---------------
__global__ __launch_bounds__(256) void conv1(const float* __restrict__ s,
                                             u16* __restrict__ d) {
  size_t idx = ((size_t)blockIdx.x * 256 + threadIdx.x) * 8;
  float4 a = *(const float4*)(s + idx);
  float4 b = *(const float4*)(s + idx + 4);
  float v[8] = {a.x, a.y, a.z, a.w, b.x, b.y, b.z, b.w};
  union { u16 q[8]; uint4 u; } pk;
#pragma unroll
  for (int i = 0; i < 8; ++i) pk.q[i] = f2b(v[i]);
  *(uint4*)(d + idx) = pk.u;
}

// ---------------- bf16 MFMA GEMM: C = A @ B^T (+bias)(+res)(gelu) ----------
template <bool GELU, bool RES32, bool RESB, bool OUT32, bool OUTB>
__global__ __launch_bounds__(256) void gemm_bt(
    const u16* __restrict__ A, const u16* __restrict__ B,
    const float* __restrict__ bias, const float* __restrict__ res32,
    const u16* __restrict__ resb, float* __restrict__ out32,
    u16* __restrict__ outb, int M, int N, int K) {
  __shared__ u16 lA[128 * 32];
  __shared__ u16 lB[128 * 32];
  const int tid = threadIdx.x;
  const int lane = tid & 63, wv = tid >> 6;
  const int m0 = blockIdx.y * 128, n0 = blockIdx.x * 128;
  const int wm = (wv >> 1) * 64, wn = (wv & 1) * 64;
  const int lrow = lane & 15;
  const int koff = (lane >> 4) * 8;
  const int rA = tid >> 2;
  const int cA = (tid & 3) * 8;

  f32x4 zero4 = {0.f, 0.f, 0.f, 0.f};
  f32x4 acc[4][4];
#pragma unroll
  for (int a = 0; a < 4; ++a)
#pragma unroll
    for (int b = 0; b < 4; ++b) acc[a][b] = zero4;

  for (int kt = 0; kt < K; kt += 32) {
    const u16* gA = A + (size_t)m0 * K + kt;
    const u16* gB = B + (size_t)n0 * K + kt;
#pragma unroll
    for (int it = 0; it < 2; ++it) {
      int row = it * 64 + rA;
      int c = it * 256 + tid;
      g2l16(gA + (size_t)row * K + cA, (char*)lA + (size_t)c * 16);
      g2l16(gB + (size_t)row * K + cA, (char*)lB + (size_t)c * 16);
    }
    __syncthreads();
    bf16x8 af[4], bfr[4];
#pragma unroll
    for (int f = 0; f < 4; ++f)
      af[f] = *(const bf16x8*)&lA[(wm + f * 16 + lrow) * 32 + koff];
#pragma unroll
    for (int f = 0; f < 4; ++f)
      bfr[f] = *(const bf16x8*)&lB[(wn + f * 16 + lrow) * 32 + koff];
#pragma unroll
    for (int fm = 0; fm < 4; ++fm)
#pragma unroll
      for (int fn = 0; fn < 4; ++fn)
        acc[fm][fn] = __builtin_amdgcn_mfma_f32_16x16x32_bf16(af[fm], bfr[fn], acc[fm][fn], 0, 0, 0);
    __syncthreads();
  }

#pragma unroll
  for (int fn = 0; fn < 4; ++fn) {
    int gcol = n0 + wn + fn * 16 + lrow;
    float bia = bias[gcol];
#pragma unroll
    for (int fm = 0; fm < 4; ++fm) {
#pragma unroll
      for (int r = 0; r < 4; ++r) {
        int grow = m0 + wm + fm * 16 + (lane >> 4) * 4 + r;
        size_t gi = (size_t)grow * N + gcol;
        float c = acc[fm][fn][r] + bia;
        if (RES32) c += res32[gi];
        if (RESB) c += b2f(resb[gi]);
        if (GELU) c = 0.5f * c * (1.0f + erff(c * 0.70710678118654752f));
        if (OUT32) out32[gi] = c;
        if (OUTB) outb[gi] = f2b(c);
      }
    }
  }
}

// ---------------- MFMA local windowed causal attention (window=64) ----------
// qkv: [rows][1536] bf16 (q|k|v), rows chunk-relative. Block = 4 waves, each
// wave = 16 queries of one (batch, head). Keys per wave: 80 = 5x16 blocks.
// V^T tile: 144 keys (i0-64 .. i0+79 clamped) so wave w reads at +16*w and
// the zero-P pad columns (local keys 80..95) still land on initialized LDS.
__global__ __launch_bounds__(256) void local_attn_mfma(const u16* __restrict__ qkv,
                                                       u16* __restrict__ outb) {
  __shared__ u16 vt[64][152];      // V^T: [dim][key 0..143, pad->152 (16B ok)]
  __shared__ u16 pb[4][16][104];   // per-wave P: [query][key 0..95 pad 104]
  const int tid = threadIdx.x;
  const int lane = tid & 63, w = tid >> 6;
  const int c = lane & 15, quad = lane >> 4;
  const int bx = blockIdx.x;
  const int qb = bx & 7, h = (bx >> 3) & 7, bb = bx >> 6;
  const int i0 = qb * 64;
  const int hc = h * 64;
  const size_t rbase = (size_t)bb * 512;

  // ---- stage V^T keys r=0..143 (global key i0-64+r, clamped) ----
  {
    int r = tid >> 1;              // 0..127
    int d0 = (tid & 1) * 32;
    int key = i0 - 64 + r;
    if (key < 0) key = 0;
    if (key > 511) key = 511;
    const u16* Vr = qkv + (rbase + key) * 1536 + 1024 + hc + d0;
#pragma unroll
    for (int g = 0; g < 4; ++g) {
      union { u16 q[8]; uint4 u; } vv;
      vv.u = *(const uint4*)(Vr + g * 8);
#pragma unroll
      for (int j = 0; j < 8; ++j) vt[d0 + g * 8 + j][r] = vv.q[j];
    }
    if (tid < 128) {               // keys 128..143, 8 dims per thread
      int r2 = 128 + (tid >> 3);
      int d2 = (tid & 7) * 8;
      int key2 = i0 - 64 + r2;
      if (key2 < 0) key2 = 0;
      if (key2 > 511) key2 = 511;
      const u16* Vr2 = qkv + (rbase + key2) * 1536 + 1024 + hc + d2;
      union { u16 q[8]; uint4 u; } vv2;
      vv2.u = *(const uint4*)Vr2;
#pragma unroll
      for (int j = 0; j < 8; ++j) vt[d2 + j][r2] = vv2.q[j];
    }
  }
  __syncthreads();

  const int i0w = i0 + 16 * w;     // wave's first query
  const int kg0 = i0w - 64;        // wave's first key

  // ---- Q A-frags (m=lane&15=query, k=quad*8+j) ----
  bf16x8 qf0, qf1;
  {
    const u16* Qr = qkv + (rbase + i0w + c) * 1536 + hc + quad * 8;
    qf0 = *(const bf16x8*)Qr;
    qf1 = *(const bf16x8*)(Qr + 32);
  }

  // ---- S = Q K^T : 5 key blocks x 2 k-tiles ----
  f32x4 s[5];
#pragma unroll
  for (int kb = 0; kb < 5; ++kb) {
    int key = kg0 + kb * 16 + c; if (key < 0) key = 0;
    const u16* Kr = qkv + (rbase + key) * 1536 + 512 + hc + quad * 8;
    bf16x8 k0 = *(const bf16x8*)Kr;
    bf16x8 k1 = *(const bf16x8*)(Kr + 32);
    f32x4 z = {0.f, 0.f, 0.f, 0.f};
    z = __builtin_amdgcn_mfma_f32_16x16x32_bf16(qf0, k0, z, 0, 0, 0);
    s[kb] = __builtin_amdgcn_mfma_f32_16x16x32_bf16(qf1, k1, z, 0, 0, 0);
  }

  // ---- mask + scale (allowed: query-64 <= key <= query, key>=0) ----
  float mx[4];
#pragma unroll
  for (int r = 0; r < 4; ++r) {
    int row = quad * 4 + r;
    float m = -1e30f;
#pragma unroll
    for (int kb = 0; kb < 5; ++kb) {
      float v = s[kb][r] * 0.125f;
      int key = kg0 + kb * 16 + c;
      bool ok = key >= 0;
      if (kb == 0) ok = ok && (c >= row);   // lower edge of window
      if (kb == 4) ok = ok && (c <= row);   // causal edge
      v = ok ? v : -1e30f;
      s[kb][r] = v;
      m = fmaxf(m, v);
    }
    mx[r] = m;
  }
#pragma unroll
  for (int o = 1; o <= 8; o <<= 1)
#pragma unroll
    for (int r = 0; r < 4; ++r) mx[r] = fmaxf(mx[r], __shfl_xor(mx[r], o));

  float l[4] = {0.f, 0.f, 0.f, 0.f};
#pragma unroll
  for (int kb = 0; kb < 5; ++kb)
#pragma unroll
    for (int r = 0; r < 4; ++r) {
      u16 pq = f2b(__expf(s[kb][r] - mx[r]));
      l[r] += b2f(pq);  // denominator from the rounded P that PV will use
      pb[w][quad * 4 + r][kb * 16 + c] = pq;
    }
#pragma unroll
  for (int r = 0; r < 4; ++r) pb[w][quad * 4 + r][80 + c] = 0;  // zero pad
#pragma unroll
  for (int o = 1; o <= 8; o <<= 1)
#pragma unroll
    for (int r = 0; r < 4; ++r) l[r] += __shfl_xor(l[r], o);
  float inv[4];
#pragma unroll
  for (int r = 0; r < 4; ++r) inv[r] = 1.f / l[r];

  // ---- O = P V : 3 k-tiles x 4 dim-blocks (same-wave LDS, no barrier) ----
  f32x4 o4[4];
#pragma unroll
  for (int nb = 0; nb < 4; ++nb) o4[nb] = f32x4{0.f, 0.f, 0.f, 0.f};
#pragma unroll
  for (int kt = 0; kt < 3; ++kt) {
    bf16x8 pa = *(const bf16x8*)&pb[w][c][kt * 32 + quad * 8];
#pragma unroll
    for (int nb = 0; nb < 4; ++nb) {
      // key offset in vt = 16*w + local key (THE R3 FIX)
      bf16x8 vb = *(const bf16x8*)&vt[nb * 16 + c][16 * w + kt * 32 + quad * 8];
      o4[nb] = __builtin_amdgcn_mfma_f32_16x16x32_bf16(pa, vb, o4[nb], 0, 0, 0);
    }
  }
#pragma unroll
  for (int nb = 0; nb < 4; ++nb)
#pragma unroll
    for (int r = 0; r < 4; ++r) {
      int seq = i0w + quad * 4 + r;
      outb[(rbase + seq) * 512 + hc + nb * 16 + c] = f2b(o4[nb][r] * inv[r]);
    }
}

// ---------------- MFMA global attention over 32 anchors ---------------------
// qg: [rows][512] bf16 chunk-relative; kvg: [32*nb][1024] bf16 (k|v).
// Block = 4 waves x 16 queries, one (batch, head). All waves share the same
// 32 anchor keys (no per-wave key offset).
__global__ __launch_bounds__(256) void global_attn_mfma(const u16* __restrict__ qg,
                                                        const u16* __restrict__ kvg,
                                                        u16* __restrict__ outb) {
  __shared__ u16 vt[64][40];       // V^T [dim][key 0..31 pad 40]
  __shared__ u16 pb[4][16][40];
  const int tid = threadIdx.x;
  const int lane = tid & 63, w = tid >> 6;
  const int c = lane & 15, quad = lane >> 4;
  const int bx = blockIdx.x;
  const int qb = bx & 7, h = (bx >> 3) & 7, bb = bx >> 6;
  const int i0 = qb * 64;
  const int hc = h * 64;
  const size_t rbase = (size_t)bb * 512;

  {
    int r = tid >> 3;              // 0..31
    int d0 = (tid & 7) * 8;
    const u16* Vr = kvg + ((size_t)bb * 32 + r) * 1024 + 512 + hc + d0;
    union { u16 q[8]; uint4 u; } vv;
    vv.u = *(const uint4*)Vr;
#pragma unroll
    for (int j = 0; j < 8; ++j) vt[d0 + j][r] = vv.q[j];
  }
  __syncthreads();

  const int i0w = i0 + 16 * w;
  bf16x8 qf0, qf1;
  {
    const u16* Qr = qg + (rbase + i0w + c) * 512 + hc + quad * 8;
    qf0 = *(const bf16x8*)Qr;
    qf1 = *(const bf16x8*)(Qr + 32);
  }
  f32x4 s[2];
#pragma unroll
  for (int kb = 0; kb < 2; ++kb) {
    const u16* Kr = kvg + ((size_t)bb * 32 + kb * 16 + c) * 1024 + hc + quad * 8;
    bf16x8 k0 = *(const bf16x8*)Kr;
    bf16x8 k1 = *(const bf16x8*)(Kr + 32);
    f32x4 z = {0.f, 0.f, 0.f, 0.f};
    z = __builtin_amdgcn_mfma_f32_16x16x32_bf16(qf0, k0, z, 0, 0, 0);
    s[kb] = __builtin_amdgcn_mfma_f32_16x16x32_bf16(qf1, k1, z, 0, 0, 0);
  }
  float mx[4];
#pragma unroll
  for (int r = 0; r < 4; ++r)
    mx[r] = fmaxf(s[0][r] * 0.125f, s[1][r] * 0.125f);
#pragma unroll
  for (int o = 1; o <= 8; o <<= 1)
#pragma unroll
    for (int r = 0; r < 4; ++r) mx[r] = fmaxf(mx[r], __shfl_xor(mx[r], o));
  float l[4] = {0.f, 0.f, 0.f, 0.f};
#pragma unroll
  for (int kb = 0; kb < 2; ++kb)
#pragma unroll
    for (int r = 0; r < 4; ++r) {
      u16 pq = f2b(__expf(s[kb][r] * 0.125f - mx[r]));
      l[r] += b2f(pq);
      pb[w][quad * 4 + r][kb * 16 + c] = pq;
    }
#pragma unroll
  for (int o = 1; o <= 8; o <<= 1)
#pragma unroll
    for (int r = 0; r < 4; ++r) l[r] += __shfl_xor(l[r], o);
  float inv[4];
#pragma unroll
  for (int r = 0; r < 4; ++r) inv[r] = 1.f / l[r];

  f32x4 o4[4];
#pragma unroll
  for (int nb = 0; nb < 4; ++nb) o4[nb] = f32x4{0.f, 0.f, 0.f, 0.f};
  bf16x8 pa = *(const bf16x8*)&pb[w][c][quad * 8];
#pragma unroll
  for (int nb = 0; nb < 4; ++nb) {
    bf16x8 vb = *(const bf16x8*)&vt[nb * 16 + c][quad * 8];
    o4[nb] = __builtin_amdgcn_mfma_f32_16x16x32_bf16(pa, vb, o4[nb], 0, 0, 0);
  }
#pragma unroll
  for (int nb = 0; nb < 4; ++nb)
#pragma unroll
    for (int r = 0; r < 4; ++r) {
      int seq = i0w + quad * 4 + r;
      outb[(rbase + seq) * 512 + hc + nb * 16 + c] = f2b(o4[nb][r] * inv[r]);
    }
}

// ---------------- LayerNorm over 512 cols, one wave per row -----------------
__global__ __launch_bounds__(256) void ln_b2b(const u16* __restrict__ in,
                                              const float* __restrict__ gg,
                                              const float* __restrict__ bb,
                                              u16* __restrict__ outb) {
  const int lane = threadIdx.x & 63;
  const size_t row = (size_t)blockIdx.x * 4 + (threadIdx.x >> 6);
  union { u16 q[8]; uint4 u; } pk;
  pk.u = *(const uint4*)(in + row * 512 + lane * 8);
  float v[8];
#pragma unroll
  for (int e = 0; e < 8; ++e) v[e] = b2f(pk.q[e]);
  float sm = 0.f, sq = 0.f;
#pragma unroll
  for (int e = 0; e < 8; ++e) { sm += v[e]; sq += v[e] * v[e]; }
#pragma unroll
  for (int o = 32; o; o >>= 1) { sm += __shfl_xor(sm, o); sq += __shfl_xor(sq, o); }
  float mean = sm * (1.0f / 512.0f);
  float var = sq * (1.0f / 512.0f) - mean * mean;
  float rs = rsqrtf(var + 1e-5f);
  float4 ga = *(const float4*)(gg + lane * 8);
  float4 gb = *(const float4*)(gg + lane * 8 + 4);
  float4 ba = *(const float4*)(bb + lane * 8);
  float4 bbv = *(const float4*)(bb + lane * 8 + 4);
  float gv[8] = {ga.x, ga.y, ga.z, ga.w, gb.x, gb.y, gb.z, gb.w};
  float bv[8] = {ba.x, ba.y, ba.z, ba.w, bbv.x, bbv.y, bbv.z, bbv.w};
  union { u16 q[8]; uint4 u; } po;
#pragma unroll
  for (int e = 0; e < 8; ++e) po.q[e] = f2b((v[e] - mean) * rs * gv[e] + bv[e]);
  *(uint4*)(outb + row * 512 + lane * 8) = po.u;
}

__global__ __launch_bounds__(256) void ln_f2f(const float* __restrict__ in,
                                              const float* __restrict__ gg,
                                              const float* __restrict__ bb,
                                              float* __restrict__ out) {
  const int lane = threadIdx.x & 63;
  const size_t row = (size_t)blockIdx.x * 4 + (threadIdx.x >> 6);
  const float* p = in + row * 512 + lane * 8;
  float4 a = *(const float4*)p;
  float4 b = *(const float4*)(p + 4);
  float v[8] = {a.x, a.y, a.z, a.w, b.x, b.y, b.z, b.w};
  float sm = 0.f, sq = 0.f;
#pragma unroll
  for (int e = 0; e < 8; ++e) { sm += v[e]; sq += v[e] * v[e]; }
#pragma unroll
  for (int o = 32; o; o >>= 1) { sm += __shfl_xor(sm, o); sq += __shfl_xor(sq, o); }
  float mean = sm * (1.0f / 512.0f);
  float var = sq * (1.0f / 512.0f) - mean * mean;
  float rs = rsqrtf(var + 1e-5f);
  float4 ga = *(const float4*)(gg + lane * 8);
  float4 gb = *(const float4*)(gg + lane * 8 + 4);
  float4 ba = *(const float4*)(bb + lane * 8);
  float4 bbv = *(const float4*)(bb + lane * 8 + 4);
  float gv[8] = {ga.x, ga.y, ga.z, ga.w, gb.x, gb.y, gb.z, gb.w};
  float bv[8] = {ba.x, ba.y, ba.z, ba.w, bbv.x, bbv.y, bbv.z, bbv.w};
  float r[8];
#pragma unroll
  for (int e = 0; e < 8; ++e) r[e] = (v[e] - mean) * rs * gv[e] + bv[e];
  float4 r1 = {r[0], r[1], r[2], r[3]};
  float4 r2 = {r[4], r[5], r[6], r[7]};
  *(float4*)(out + row * 512 + lane * 8) = r1;
  *(float4*)(out + row * 512 + lane * 8 + 4) = r2;
}

// ---------------- driver -----------------------------------------------------
extern "C" void kernel_launch(void* const* d_in, const int* in_sizes, int n_in,
                              void* d_out, int out_size, void* d_ws, size_t ws_size,
                              hipStream_t stream) {
  const float* x      = (const float*)d_in[0];
  const float* anchors= (const float*)d_in[1];
  const float* lw_in  = (const float*)d_in[2];
  const float* lb_in  = (const float*)d_in[3];
  const float* lw_out = (const float*)d_in[4];
  const float* lb_out = (const float*)d_in[5];
  const float* gw_in  = (const float*)d_in[6];
  const float* gb_in  = (const float*)d_in[7];
  const float* gw_out = (const float*)d_in[8];
  const float* gb_out = (const float*)d_in[9];
  const float* w1     = (const float*)d_in[10];
  const float* b1     = (const float*)d_in[11];
  const float* w2     = (const float*)d_in[12];
  const float* b2     = (const float*)d_in[13];
  const float* g1     = (const float*)d_in[14];
  const float* be1    = (const float*)d_in[15];
  const float* g2     = (const float*)d_in[16];
  const float* be2    = (const float*)d_in[17];
  (void)in_sizes; (void)n_in; (void)out_size;
  float* out = (float*)d_out;

  char* ws = (char*)d_ws;
  size_t o = 0;
  auto nxt = [&](size_t bytes) { char* p = ws + o; o += bytes; return p; };
  u16* lwib = (u16*)nxt((size_t)1536 * 512 * 2);
  u16* lwob = (u16*)nxt((size_t)512 * 512 * 2);
  u16* gwib = (u16*)nxt((size_t)1536 * 512 * 2);
  u16* gwob = (u16*)nxt((size_t)512 * 512 * 2);
  u16* w1b  = (u16*)nxt((size_t)2048 * 512 * 2);
  u16* w2b  = (u16*)nxt((size_t)512 * 2048 * 2);
  u16* ab   = (u16*)nxt((size_t)2048 * 512 * 2);
  u16* kvgb = (u16*)nxt((size_t)2048 * 1024 * 2);
  const size_t wbytes = o;

  int nc = 1;
  while (wbytes + (size_t)(32768 / nc) * 6144 > ws_size && nc < 32) nc <<= 1;
  const int Mc = 32768 / nc;
  const int nBat = Mc / 512;
  u16* BIGb = (u16*)nxt((size_t)Mc * 4096);
  u16* Pb   = (u16*)nxt((size_t)Mc * 1024);
  u16* Qb   = (u16*)nxt((size_t)Mc * 1024);
  u16* Sb   = BIGb + (size_t)Mc * 1536;

  conv1<<<384, 256, 0, stream>>>(lw_in, lwib);
  conv1<<<128, 256, 0, stream>>>(lw_out, lwob);
  conv1<<<384, 256, 0, stream>>>(gw_in, gwib);
  conv1<<<128, 256, 0, stream>>>(gw_out, gwob);
  conv1<<<512, 256, 0, stream>>>(w1, w1b);
  conv1<<<512, 256, 0, stream>>>(w2, w2b);
  conv1<<<512, 256, 0, stream>>>(anchors, ab);
  gemm_bt<false, false, false, false, true><<<dim3(8, 16), 256, 0, stream>>>(
      ab, gwib + 512 * 512, gb_in + 512, nullptr, nullptr, nullptr, kvgb, 2048, 1024, 512);

  for (int ck = 0; ck < nc; ++ck) {
    const size_t r0 = (size_t)ck * Mc;
    const float* xck = x + r0 * 512;
    conv1<<<Mc / 4, 256, 0, stream>>>(xck, Pb);
    gemm_bt<false, false, false, false, true><<<dim3(12, Mc / 128), 256, 0, stream>>>(
        Pb, lwib, lb_in, nullptr, nullptr, nullptr, BIGb, Mc, 1536, 512);
    local_attn_mfma<<<nBat * 64, 256, 0, stream>>>(BIGb, Sb);
    gemm_bt<false, true, false, false, true><<<dim3(4, Mc / 128), 256, 0, stream>>>(
        Sb, lwob, lb_out, xck, nullptr, nullptr, Qb, Mc, 512, 512);
    gemm_bt<false, false, false, false, true><<<dim3(4, Mc / 128), 256, 0, stream>>>(
        Qb, gwib, gb_in, nullptr, nullptr, nullptr, Pb, Mc, 512, 512);
    global_attn_mfma<<<nBat * 64, 256, 0, stream>>>(Pb, kvgb + (r0 / 512) * 32 * 1024, Sb);
    gemm_bt<false, false, true, false, true><<<dim3(4, Mc / 128), 256, 0, stream>>>(
        Sb, gwob, gb_out, nullptr, Qb, nullptr, Pb, Mc, 512, 512);
    ln_b2b<<<Mc / 4, 256, 0, stream>>>(Pb, g1, be1, Qb);
    gemm_bt<true, false, false, false, true><<<dim3(16, Mc / 128), 256, 0, stream>>>(
        Qb, w1b, b1, nullptr, nullptr, nullptr, BIGb, Mc, 2048, 512);
    gemm_bt<false, false, true, true, false><<<dim3(4, Mc / 128), 256, 0, stream>>>(
        BIGb, w2b, b2, nullptr, Qb, out + r0 * 512, nullptr, Mc, 512, 2048);
    ln_f2f<<<Mc / 4, 256, 0, stream>>>(out + r0 * 512, g2, be2, out + r0 * 512);
  }
}

// Round 5
// 728.865 us; speedup vs baseline: 1.9293x; 1.0291x over previous
//
#include <hip/hip_runtime.h>
#include <cmath>

// SparseCausalAttentionBlock on MI355X (gfx950).
// Round 5: vectorized GEMM epilogue. R4 profile: top GEMMs at 152us with
// WRITE_SIZE 231MB (~3x logical output -> partial-line write amplification
// from 2B scalar bf16 stores), MfmaUtil 19%, VALUBusy 54%. Epilogue now
// stages each wave's 16x64 C tile through LDS (stride 68 floats) and emits
// full-line 16B/lane loads+stores. K-loop/attention/LN unchanged from R4.

typedef unsigned short u16;
typedef unsigned int u32;
typedef __bf16 bf16_t;
typedef bf16_t bf16x8 __attribute__((ext_vector_type(8)));
typedef float f32x4 __attribute__((ext_vector_type(4)));

#define DEV __device__ __forceinline__

DEV u16 f2b(float f) {  // fp32 -> bf16 RNE
  u32 u = __float_as_uint(f);
  u32 r = u + 0x7fffu + ((u >> 16) & 1u);
  return (u16)(r >> 16);
}
DEV float b2f(u16 b) { return __uint_as_float(((u32)b) << 16); }

DEV void g2l16(const void* g, void* l) {
  // async global->LDS, 16B/lane; LDS dest = wave-uniform base + lane*16
  __builtin_amdgcn_global_load_lds((const __attribute__((address_space(1))) void*)g,
                                   (__attribute__((address_space(3))) void*)l,
                                   16, 0, 0);
}

// ---------------- fp32 -> bf16 converter (2048 elems / block) ---------------
__global__ __launch_bounds__(256) void conv1(const float* __restrict__ s,
                                             u16* __restrict__ d) {
  size_t idx = ((size_t)blockIdx.x * 256 + threadIdx.x) * 8;
  float4 a = *(const float4*)(s + idx);
  float4 b = *(const float4*)(s + idx + 4);
  float v[8] = {a.x, a.y, a.z, a.w, b.x, b.y, b.z, b.w};
  union { u16 q[8]; uint4 u; } pk;
#pragma unroll
  for (int i = 0; i < 8; ++i) pk.q[i] = f2b(v[i]);
  *(uint4*)(d + idx) = pk.u;
}

// ---------------- bf16 MFMA GEMM: C = A @ B^T (+bias)(+res)(gelu) ----------
// Tile 128x128x32, 256 thr = 4 waves (2x2). Epilogue: per-wave LDS staging
// (16x64 fp32, stride 68) -> each lane owns 1 row x 16 contiguous cols ->
// vectorized residual/bias loads and full-line stores.
template <bool GELU, bool RES32, bool RESB, bool OUT32, bool OUTB>
__global__ __launch_bounds__(256) void gemm_bt(
    const u16* __restrict__ A, const u16* __restrict__ B,
    const float* __restrict__ bias, const float* __restrict__ res32,
    const u16* __restrict__ resb, float* __restrict__ out32,
    u16* __restrict__ outb, int M, int N, int K) {
  __shared__ __align__(16) char smem[17408];  // lA 8K | lB 8K ; epi: 4x4352
  u16* lA = (u16*)smem;
  u16* lB = (u16*)(smem + 8192);
  const int tid = threadIdx.x;
  const int lane = tid & 63, wv = tid >> 6;
  const int m0 = blockIdx.y * 128, n0 = blockIdx.x * 128;
  const int wm = (wv >> 1) * 64, wn = (wv & 1) * 64;
  const int lrow = lane & 15;
  const int quad = lane >> 4;
  const int koff = quad * 8;
  const int rA = tid >> 2;
  const int cA = (tid & 3) * 8;

  f32x4 zero4 = {0.f, 0.f, 0.f, 0.f};
  f32x4 acc[4][4];
#pragma unroll
  for (int a = 0; a < 4; ++a)
#pragma unroll
    for (int b = 0; b < 4; ++b) acc[a][b] = zero4;

  for (int kt = 0; kt < K; kt += 32) {
    const u16* gA = A + (size_t)m0 * K + kt;
    const u16* gB = B + (size_t)n0 * K + kt;
#pragma unroll
    for (int it = 0; it < 2; ++it) {
      int row = it * 64 + rA;
      int c = it * 256 + tid;
      g2l16(gA + (size_t)row * K + cA, (char*)lA + (size_t)c * 16);
      g2l16(gB + (size_t)row * K + cA, (char*)lB + (size_t)c * 16);
    }
    __syncthreads();
    bf16x8 af[4], bfr[4];
#pragma unroll
    for (int f = 0; f < 4; ++f)
      af[f] = *(const bf16x8*)&lA[(wm + f * 16 + lrow) * 32 + koff];
#pragma unroll
    for (int f = 0; f < 4; ++f)
      bfr[f] = *(const bf16x8*)&lB[(wn + f * 16 + lrow) * 32 + koff];
#pragma unroll
    for (int fm = 0; fm < 4; ++fm)
#pragma unroll
      for (int fn = 0; fn < 4; ++fn)
        acc[fm][fn] = __builtin_amdgcn_mfma_f32_16x16x32_bf16(af[fm], bfr[fn], acc[fm][fn], 0, 0, 0);
    __syncthreads();
  }
  // after final barrier all LDS reads are drained -> reuse smem per wave
  float* cw = (float*)(smem + (size_t)wv * 4352);  // 16 rows x 68 floats

  const int row16 = lane >> 2;       // 0..15: lane's row within fm-block
  const int c0 = (lane & 3) * 16;    // lane's 16-col chunk within wave tile
  const int gcb = n0 + wn + c0;
  float bias16[16];
#pragma unroll
  for (int t = 0; t < 4; ++t) {
    float4 b4 = *(const float4*)(bias + gcb + t * 4);
    bias16[t * 4 + 0] = b4.x; bias16[t * 4 + 1] = b4.y;
    bias16[t * 4 + 2] = b4.z; bias16[t * 4 + 3] = b4.w;
  }

#pragma unroll
  for (int fm = 0; fm < 4; ++fm) {
    // scatter acc (C-layout: row=quad*4+r, col=fn*16+lrow) into LDS
#pragma unroll
    for (int fn = 0; fn < 4; ++fn)
#pragma unroll
      for (int r = 0; r < 4; ++r)
        cw[(quad * 4 + r) * 68 + fn * 16 + lrow] = acc[fm][fn][r];
    // gather back: 16 contiguous cols of one row (same-wave LDS, in-order DS)
    const int grow = m0 + wm + fm * 16 + row16;
    const size_t gbase = (size_t)grow * N + gcb;
    const float* crp = &cw[row16 * 68 + c0];
    float v[16];
#pragma unroll
    for (int t = 0; t < 4; ++t) {
      f32x4 q = *(const f32x4*)(crp + t * 4);
      v[t * 4 + 0] = q[0] + bias16[t * 4 + 0];
      v[t * 4 + 1] = q[1] + bias16[t * 4 + 1];
      v[t * 4 + 2] = q[2] + bias16[t * 4 + 2];
      v[t * 4 + 3] = q[3] + bias16[t * 4 + 3];
    }
    if (RES32) {
#pragma unroll
      for (int t = 0; t < 4; ++t) {
        float4 rr = *(const float4*)(res32 + gbase + t * 4);
        v[t * 4 + 0] += rr.x; v[t * 4 + 1] += rr.y;
        v[t * 4 + 2] += rr.z; v[t * 4 + 3] += rr.w;
      }
    }
    if (RESB) {
#pragma unroll
      for (int t = 0; t < 2; ++t) {
        union { u16 q[8]; uint4 u; } rb;
        rb.u = *(const uint4*)(resb + gbase + t * 8);
#pragma unroll
        for (int j = 0; j < 8; ++j) v[t * 8 + j] += b2f(rb.q[j]);
      }
    }
    if (GELU) {
#pragma unroll
      for (int e = 0; e < 16; ++e)
        v[e] = 0.5f * v[e] * (1.0f + erff(v[e] * 0.70710678118654752f));
    }
    if (OUT32) {
#pragma unroll
      for (int t = 0; t < 4; ++t) {
        float4 w4 = {v[t * 4 + 0], v[t * 4 + 1], v[t * 4 + 2], v[t * 4 + 3]};
        *(float4*)(out32 + gbase + t * 4) = w4;
      }
    }
    if (OUTB) {
#pragma unroll
      for (int t = 0; t < 2; ++t) {
        union { u16 q[8]; uint4 u; } pk;
#pragma unroll
        for (int j = 0; j < 8; ++j) pk.q[j] = f2b(v[t * 8 + j]);
        *(uint4*)(outb + gbase + t * 8) = pk.u;
      }
    }
  }
}

// ---------------- MFMA local windowed causal attention (window=64) ----------
__global__ __launch_bounds__(256) void local_attn_mfma(const u16* __restrict__ qkv,
                                                       u16* __restrict__ outb) {
  __shared__ u16 vt[64][152];      // V^T: [dim][key 0..143, pad->152]
  __shared__ u16 pb[4][16][104];   // per-wave P: [query][key 0..95 pad 104]
  const int tid = threadIdx.x;
  const int lane = tid & 63, w = tid >> 6;
  const int c = lane & 15, quad = lane >> 4;
  const int bx = blockIdx.x;
  const int qb = bx & 7, h = (bx >> 3) & 7, bb = bx >> 6;
  const int i0 = qb * 64;
  const int hc = h * 64;
  const size_t rbase = (size_t)bb * 512;

  {
    int r = tid >> 1;              // 0..127
    int d0 = (tid & 1) * 32;
    int key = i0 - 64 + r;
    if (key < 0) key = 0;
    if (key > 511) key = 511;
    const u16* Vr = qkv + (rbase + key) * 1536 + 1024 + hc + d0;
#pragma unroll
    for (int g = 0; g < 4; ++g) {
      union { u16 q[8]; uint4 u; } vv;
      vv.u = *(const uint4*)(Vr + g * 8);
#pragma unroll
      for (int j = 0; j < 8; ++j) vt[d0 + g * 8 + j][r] = vv.q[j];
    }
    if (tid < 128) {               // keys 128..143
      int r2 = 128 + (tid >> 3);
      int d2 = (tid & 7) * 8;
      int key2 = i0 - 64 + r2;
      if (key2 < 0) key2 = 0;
      if (key2 > 511) key2 = 511;
      const u16* Vr2 = qkv + (rbase + key2) * 1536 + 1024 + hc + d2;
      union { u16 q[8]; uint4 u; } vv2;
      vv2.u = *(const uint4*)Vr2;
#pragma unroll
      for (int j = 0; j < 8; ++j) vt[d2 + j][r2] = vv2.q[j];
    }
  }
  __syncthreads();

  const int i0w = i0 + 16 * w;
  const int kg0 = i0w - 64;

  bf16x8 qf0, qf1;
  {
    const u16* Qr = qkv + (rbase + i0w + c) * 1536 + hc + quad * 8;
    qf0 = *(const bf16x8*)Qr;
    qf1 = *(const bf16x8*)(Qr + 32);
  }

  f32x4 s[5];
#pragma unroll
  for (int kb = 0; kb < 5; ++kb) {
    int key = kg0 + kb * 16 + c; if (key < 0) key = 0;
    const u16* Kr = qkv + (rbase + key) * 1536 + 512 + hc + quad * 8;
    bf16x8 k0 = *(const bf16x8*)Kr;
    bf16x8 k1 = *(const bf16x8*)(Kr + 32);
    f32x4 z = {0.f, 0.f, 0.f, 0.f};
    z = __builtin_amdgcn_mfma_f32_16x16x32_bf16(qf0, k0, z, 0, 0, 0);
    s[kb] = __builtin_amdgcn_mfma_f32_16x16x32_bf16(qf1, k1, z, 0, 0, 0);
  }

  float mx[4];
#pragma unroll
  for (int r = 0; r < 4; ++r) {
    int row = quad * 4 + r;
    float m = -1e30f;
#pragma unroll
    for (int kb = 0; kb < 5; ++kb) {
      float v = s[kb][r] * 0.125f;
      int key = kg0 + kb * 16 + c;
      bool ok = key >= 0;
      if (kb == 0) ok = ok && (c >= row);
      if (kb == 4) ok = ok && (c <= row);
      v = ok ? v : -1e30f;
      s[kb][r] = v;
      m = fmaxf(m, v);
    }
    mx[r] = m;
  }
#pragma unroll
  for (int o = 1; o <= 8; o <<= 1)
#pragma unroll
    for (int r = 0; r < 4; ++r) mx[r] = fmaxf(mx[r], __shfl_xor(mx[r], o));

  float l[4] = {0.f, 0.f, 0.f, 0.f};
#pragma unroll
  for (int kb = 0; kb < 5; ++kb)
#pragma unroll
    for (int r = 0; r < 4; ++r) {
      u16 pq = f2b(__expf(s[kb][r] - mx[r]));
      l[r] += b2f(pq);
      pb[w][quad * 4 + r][kb * 16 + c] = pq;
    }
#pragma unroll
  for (int r = 0; r < 4; ++r) pb[w][quad * 4 + r][80 + c] = 0;
#pragma unroll
  for (int o = 1; o <= 8; o <<= 1)
#pragma unroll
    for (int r = 0; r < 4; ++r) l[r] += __shfl_xor(l[r], o);
  float inv[4];
#pragma unroll
  for (int r = 0; r < 4; ++r) inv[r] = 1.f / l[r];

  f32x4 o4[4];
#pragma unroll
  for (int nb = 0; nb < 4; ++nb) o4[nb] = f32x4{0.f, 0.f, 0.f, 0.f};
#pragma unroll
  for (int kt = 0; kt < 3; ++kt) {
    bf16x8 pa = *(const bf16x8*)&pb[w][c][kt * 32 + quad * 8];
#pragma unroll
    for (int nb = 0; nb < 4; ++nb) {
      bf16x8 vb = *(const bf16x8*)&vt[nb * 16 + c][16 * w + kt * 32 + quad * 8];
      o4[nb] = __builtin_amdgcn_mfma_f32_16x16x32_bf16(pa, vb, o4[nb], 0, 0, 0);
    }
  }
#pragma unroll
  for (int nb = 0; nb < 4; ++nb)
#pragma unroll
    for (int r = 0; r < 4; ++r) {
      int seq = i0w + quad * 4 + r;
      outb[(rbase + seq) * 512 + hc + nb * 16 + c] = f2b(o4[nb][r] * inv[r]);
    }
}

// ---------------- MFMA global attention over 32 anchors ---------------------
__global__ __launch_bounds__(256) void global_attn_mfma(const u16* __restrict__ qg,
                                                        const u16* __restrict__ kvg,
                                                        u16* __restrict__ outb) {
  __shared__ u16 vt[64][40];
  __shared__ u16 pb[4][16][40];
  const int tid = threadIdx.x;
  const int lane = tid & 63, w = tid >> 6;
  const int c = lane & 15, quad = lane >> 4;
  const int bx = blockIdx.x;
  const int qb = bx & 7, h = (bx >> 3) & 7, bb = bx >> 6;
  const int i0 = qb * 64;
  const int hc = h * 64;
  const size_t rbase = (size_t)bb * 512;

  {
    int r = tid >> 3;
    int d0 = (tid & 7) * 8;
    const u16* Vr = kvg + ((size_t)bb * 32 + r) * 1024 + 512 + hc + d0;
    union { u16 q[8]; uint4 u; } vv;
    vv.u = *(const uint4*)Vr;
#pragma unroll
    for (int j = 0; j < 8; ++j) vt[d0 + j][r] = vv.q[j];
  }
  __syncthreads();

  const int i0w = i0 + 16 * w;
  bf16x8 qf0, qf1;
  {
    const u16* Qr = qg + (rbase + i0w + c) * 512 + hc + quad * 8;
    qf0 = *(const bf16x8*)Qr;
    qf1 = *(const bf16x8*)(Qr + 32);
  }
  f32x4 s[2];
#pragma unroll
  for (int kb = 0; kb < 2; ++kb) {
    const u16* Kr = kvg + ((size_t)bb * 32 + kb * 16 + c) * 1024 + hc + quad * 8;
    bf16x8 k0 = *(const bf16x8*)Kr;
    bf16x8 k1 = *(const bf16x8*)(Kr + 32);
    f32x4 z = {0.f, 0.f, 0.f, 0.f};
    z = __builtin_amdgcn_mfma_f32_16x16x32_bf16(qf0, k0, z, 0, 0, 0);
    s[kb] = __builtin_amdgcn_mfma_f32_16x16x32_bf16(qf1, k1, z, 0, 0, 0);
  }
  float mx[4];
#pragma unroll
  for (int r = 0; r < 4; ++r)
    mx[r] = fmaxf(s[0][r] * 0.125f, s[1][r] * 0.125f);
#pragma unroll
  for (int o = 1; o <= 8; o <<= 1)
#pragma unroll
    for (int r = 0; r < 4; ++r) mx[r] = fmaxf(mx[r], __shfl_xor(mx[r], o));
  float l[4] = {0.f, 0.f, 0.f, 0.f};
#pragma unroll
  for (int kb = 0; kb < 2; ++kb)
#pragma unroll
    for (int r = 0; r < 4; ++r) {
      u16 pq = f2b(__expf(s[kb][r] * 0.125f - mx[r]));
      l[r] += b2f(pq);
      pb[w][quad * 4 + r][kb * 16 + c] = pq;
    }
#pragma unroll
  for (int o = 1; o <= 8; o <<= 1)
#pragma unroll
    for (int r = 0; r < 4; ++r) l[r] += __shfl_xor(l[r], o);
  float inv[4];
#pragma unroll
  for (int r = 0; r < 4; ++r) inv[r] = 1.f / l[r];

  f32x4 o4[4];
#pragma unroll
  for (int nb = 0; nb < 4; ++nb) o4[nb] = f32x4{0.f, 0.f, 0.f, 0.f};
  bf16x8 pa = *(const bf16x8*)&pb[w][c][quad * 8];
#pragma unroll
  for (int nb = 0; nb < 4; ++nb) {
    bf16x8 vb = *(const bf16x8*)&vt[nb * 16 + c][quad * 8];
    o4[nb] = __builtin_amdgcn_mfma_f32_16x16x32_bf16(pa, vb, o4[nb], 0, 0, 0);
  }
#pragma unroll
  for (int nb = 0; nb < 4; ++nb)
#pragma unroll
    for (int r = 0; r < 4; ++r) {
      int seq = i0w + quad * 4 + r;
      outb[(rbase + seq) * 512 + hc + nb * 16 + c] = f2b(o4[nb][r] * inv[r]);
    }
}

// ---------------- LayerNorm over 512 cols, one wave per row -----------------
__global__ __launch_bounds__(256) void ln_b2b(const u16* __restrict__ in,
                                              const float* __restrict__ gg,
                                              const float* __restrict__ bb,
                                              u16* __restrict__ outb) {
  const int lane = threadIdx.x & 63;
  const size_t row = (size_t)blockIdx.x * 4 + (threadIdx.x >> 6);
  union { u16 q[8]; uint4 u; } pk;
  pk.u = *(const uint4*)(in + row * 512 + lane * 8);
  float v[8];
#pragma unroll
  for (int e = 0; e < 8; ++e) v[e] = b2f(pk.q[e]);
  float sm = 0.f, sq = 0.f;
#pragma unroll
  for (int e = 0; e < 8; ++e) { sm += v[e]; sq += v[e] * v[e]; }
#pragma unroll
  for (int o = 32; o; o >>= 1) { sm += __shfl_xor(sm, o); sq += __shfl_xor(sq, o); }
  float mean = sm * (1.0f / 512.0f);
  float var = sq * (1.0f / 512.0f) - mean * mean;
  float rs = rsqrtf(var + 1e-5f);
  float4 ga = *(const float4*)(gg + lane * 8);
  float4 gb = *(const float4*)(gg + lane * 8 + 4);
  float4 ba = *(const float4*)(bb + lane * 8);
  float4 bbv = *(const float4*)(bb + lane * 8 + 4);
  float gv[8] = {ga.x, ga.y, ga.z, ga.w, gb.x, gb.y, gb.z, gb.w};
  float bv[8] = {ba.x, ba.y, ba.z, ba.w, bbv.x, bbv.y, bbv.z, bbv.w};
  union { u16 q[8]; uint4 u; } po;
#pragma unroll
  for (int e = 0; e < 8; ++e) po.q[e] = f2b((v[e] - mean) * rs * gv[e] + bv[e]);
  *(uint4*)(outb + row * 512 + lane * 8) = po.u;
}

__global__ __launch_bounds__(256) void ln_f2f(const float* __restrict__ in,
                                              const float* __restrict__ gg,
                                              const float* __restrict__ bb,
                                              float* __restrict__ out) {
  const int lane = threadIdx.x & 63;
  const size_t row = (size_t)blockIdx.x * 4 + (threadIdx.x >> 6);
  const float* p = in + row * 512 + lane * 8;
  float4 a = *(const float4*)p;
  float4 b = *(const float4*)(p + 4);
  float v[8] = {a.x, a.y, a.z, a.w, b.x, b.y, b.z, b.w};
  float sm = 0.f, sq = 0.f;
#pragma unroll
  for (int e = 0; e < 8; ++e) { sm += v[e]; sq += v[e] * v[e]; }
#pragma unroll
  for (int o = 32; o; o >>= 1) { sm += __shfl_xor(sm, o); sq += __shfl_xor(sq, o); }
  float mean = sm * (1.0f / 512.0f);
  float var = sq * (1.0f / 512.0f) - mean * mean;
  float rs = rsqrtf(var + 1e-5f);
  float4 ga = *(const float4*)(gg + lane * 8);
  float4 gb = *(const float4*)(gg + lane * 8 + 4);
  float4 ba = *(const float4*)(bb + lane * 8);
  float4 bbv = *(const float4*)(bb + lane * 8 + 4);
  float gv[8] = {ga.x, ga.y, ga.z, ga.w, gb.x, gb.y, gb.z, gb.w};
  float bv[8] = {ba.x, ba.y, ba.z, ba.w, bbv.x, bbv.y, bbv.z, bbv.w};
  float r[8];
#pragma unroll
  for (int e = 0; e < 8; ++e) r[e] = (v[e] - mean) * rs * gv[e] + bv[e];
  float4 r1 = {r[0], r[1], r[2], r[3]};
  float4 r2 = {r[4], r[5], r[6], r[7]};
  *(float4*)(out + row * 512 + lane * 8) = r1;
  *(float4*)(out + row * 512 + lane * 8 + 4) = r2;
}

// ---------------- driver -----------------------------------------------------
extern "C" void kernel_launch(void* const* d_in, const int* in_sizes, int n_in,
                              void* d_out, int out_size, void* d_ws, size_t ws_size,
                              hipStream_t stream) {
  const float* x      = (const float*)d_in[0];
  const float* anchors= (const float*)d_in[1];
  const float* lw_in  = (const float*)d_in[2];
  const float* lb_in  = (const float*)d_in[3];
  const float* lw_out = (const float*)d_in[4];
  const float* lb_out = (const float*)d_in[5];
  const float* gw_in  = (const float*)d_in[6];
  const float* gb_in  = (const float*)d_in[7];
  const float* gw_out = (const float*)d_in[8];
  const float* gb_out = (const float*)d_in[9];
  const float* w1     = (const float*)d_in[10];
  const float* b1     = (const float*)d_in[11];
  const float* w2     = (const float*)d_in[12];
  const float* b2     = (const float*)d_in[13];
  const float* g1     = (const float*)d_in[14];
  const float* be1    = (const float*)d_in[15];
  const float* g2     = (const float*)d_in[16];
  const float* be2    = (const float*)d_in[17];
  (void)in_sizes; (void)n_in; (void)out_size;
  float* out = (float*)d_out;

  char* ws = (char*)d_ws;
  size_t o = 0;
  auto nxt = [&](size_t bytes) { char* p = ws + o; o += bytes; return p; };
  u16* lwib = (u16*)nxt((size_t)1536 * 512 * 2);
  u16* lwob = (u16*)nxt((size_t)512 * 512 * 2);
  u16* gwib = (u16*)nxt((size_t)1536 * 512 * 2);
  u16* gwob = (u16*)nxt((size_t)512 * 512 * 2);
  u16* w1b  = (u16*)nxt((size_t)2048 * 512 * 2);
  u16* w2b  = (u16*)nxt((size_t)512 * 2048 * 2);
  u16* ab   = (u16*)nxt((size_t)2048 * 512 * 2);
  u16* kvgb = (u16*)nxt((size_t)2048 * 1024 * 2);
  const size_t wbytes = o;

  int nc = 1;
  while (wbytes + (size_t)(32768 / nc) * 6144 > ws_size && nc < 32) nc <<= 1;
  const int Mc = 32768 / nc;
  const int nBat = Mc / 512;
  u16* BIGb = (u16*)nxt((size_t)Mc * 4096);
  u16* Pb   = (u16*)nxt((size_t)Mc * 1024);
  u16* Qb   = (u16*)nxt((size_t)Mc * 1024);
  u16* Sb   = BIGb + (size_t)Mc * 1536;

  conv1<<<384, 256, 0, stream>>>(lw_in, lwib);
  conv1<<<128, 256, 0, stream>>>(lw_out, lwob);
  conv1<<<384, 256, 0, stream>>>(gw_in, gwib);
  conv1<<<128, 256, 0, stream>>>(gw_out, gwob);
  conv1<<<512, 256, 0, stream>>>(w1, w1b);
  conv1<<<512, 256, 0, stream>>>(w2, w2b);
  conv1<<<512, 256, 0, stream>>>(anchors, ab);
  gemm_bt<false, false, false, false, true><<<dim3(8, 16), 256, 0, stream>>>(
      ab, gwib + 512 * 512, gb_in + 512, nullptr, nullptr, nullptr, kvgb, 2048, 1024, 512);

  for (int ck = 0; ck < nc; ++ck) {
    const size_t r0 = (size_t)ck * Mc;
    const float* xck = x + r0 * 512;
    conv1<<<Mc / 4, 256, 0, stream>>>(xck, Pb);
    gemm_bt<false, false, false, false, true><<<dim3(12, Mc / 128), 256, 0, stream>>>(
        Pb, lwib, lb_in, nullptr, nullptr, nullptr, BIGb, Mc, 1536, 512);
    local_attn_mfma<<<nBat * 64, 256, 0, stream>>>(BIGb, Sb);
    gemm_bt<false, true, false, false, true><<<dim3(4, Mc / 128), 256, 0, stream>>>(
        Sb, lwob, lb_out, xck, nullptr, nullptr, Qb, Mc, 512, 512);
    gemm_bt<false, false, false, false, true><<<dim3(4, Mc / 128), 256, 0, stream>>>(
        Qb, gwib, gb_in, nullptr, nullptr, nullptr, Pb, Mc, 512, 512);
    global_attn_mfma<<<nBat * 64, 256, 0, stream>>>(Pb, kvgb + (r0 / 512) * 32 * 1024, Sb);
    gemm_bt<false, false, true, false, true><<<dim3(4, Mc / 128), 256, 0, stream>>>(
        Sb, gwob, gb_out, nullptr, Qb, nullptr, Pb, Mc, 512, 512);
    ln_b2b<<<Mc / 4, 256, 0, stream>>>(Pb, g1, be1, Qb);
    gemm_bt<true, false, false, false, true><<<dim3(16, Mc / 128), 256, 0, stream>>>(
        Qb, w1b, b1, nullptr, nullptr, nullptr, BIGb, Mc, 2048, 512);
    gemm_bt<false, false, true, true, false><<<dim3(4, Mc / 128), 256, 0, stream>>>(
        BIGb, w2b, b2, nullptr, Qb, out + r0 * 512, nullptr, Mc, 512, 2048);
    ln_f2f<<<Mc / 4, 256, 0, stream>>>(out + r0 * 512, g2, be2, out + r0 * 512);
  }
}